// Round 5
// baseline (339.549 us; speedup 1.0000x reference)
//
#include <hip/hip_runtime.h>

typedef __bf16 bf16;
typedef bf16  bf16x8 __attribute__((ext_vector_type(8)));
typedef bf16  bf16x4 __attribute__((ext_vector_type(4)));
typedef short s16x4  __attribute__((ext_vector_type(4)));
typedef float f32x4  __attribute__((ext_vector_type(4)));

#define AS1 __attribute__((address_space(1)))
#define AS3 __attribute__((address_space(3)))

#define SQLEN 2048
#define EMB   1024

// ---------------- fp32 -> bf16 convert (memory-bound) ----------------
__global__ __launch_bounds__(256) void cvt_f32_bf16(const float* __restrict__ in,
                                                    bf16* __restrict__ out, int n8) {
  int i = blockIdx.x * blockDim.x + threadIdx.x;
  if (i >= n8) return;
  const float4* p = (const float4*)in + (size_t)i * 2;
  float4 a = p[0], b = p[1];
  bf16x8 o;
  o[0] = (bf16)a.x; o[1] = (bf16)a.y; o[2] = (bf16)a.z; o[3] = (bf16)a.w;
  o[4] = (bf16)b.x; o[5] = (bf16)b.y; o[6] = (bf16)b.z; o[7] = (bf16)b.w;
  *((bf16x8*)out + i) = o;
}

// 4 weight matrices in one dispatch (blockIdx.y selects)
__global__ __launch_bounds__(256) void cvt_w4(const float* __restrict__ w0, const float* __restrict__ w1,
                                              const float* __restrict__ w2, const float* __restrict__ w3,
                                              bf16* o0, bf16* o1, bf16* o2, bf16* o3, int n8) {
  const float* in; bf16* out;
  switch (blockIdx.y) {
    case 0: in = w0; out = o0; break;
    case 1: in = w1; out = o1; break;
    case 2: in = w2; out = o2; break;
    default: in = w3; out = o3; break;
  }
  int i = blockIdx.x * blockDim.x + threadIdx.x;
  if (i >= n8) return;
  const float4* p = (const float4*)in + (size_t)i * 2;
  float4 a = p[0], b = p[1];
  bf16x8 o;
  o[0] = (bf16)a.x; o[1] = (bf16)a.y; o[2] = (bf16)a.z; o[3] = (bf16)a.w;
  o[4] = (bf16)b.x; o[5] = (bf16)b.y; o[6] = (bf16)b.z; o[7] = (bf16)b.w;
  *((bf16x8*)out + i) = o;
}

// ---------------- NT GEMM body: C[M,N] = A[M,K]*B[N,K]^T, dbuf single-barrier K-loop
// vtr (runtime, only bf16 path): store transposed as Vt[(b*1024+n)][t] where
// m = b*2048 + t. Each lane's 4 acc rows are 4 consecutive t at fixed n -> one
// bf16x4 store; 4 quads of a col form a 32B run per Vt row.
template <int OUTF32>
__device__ __forceinline__
void gemm_body(const bf16* __restrict__ A, const bf16* __restrict__ B,
               float* __restrict__ Cf, bf16* __restrict__ Cb,
               int M, int N, int K, float scale, bf16* Asl, bf16* Bsl, int vtr) {
  const int tid  = threadIdx.x;
  const int lane = tid & 63, wave = tid >> 6;
  const int quad = lane >> 4, col = lane & 15;
  const int m0 = blockIdx.x * 128, n0 = blockIdx.y * 128;
  const int wr = wave >> 1, wc = wave & 1;

  f32x4 acc[4][4];
  const f32x4 fz = {0.f, 0.f, 0.f, 0.f};
#pragma unroll
  for (int i = 0; i < 4; ++i)
#pragma unroll
    for (int j = 0; j < 4; ++j) acc[i][j] = fz;

  const int srow = lane >> 2;
  const int sk   = lane & 3;

  auto stage = [&](int buf, int k0) {
#pragma unroll
    for (int r = 0; r < 2; ++r) {
      const int c      = wave * 2 + r;
      const int row    = c * 16 + srow;
      const int gchunk = sk ^ (row & 3);
      const bf16* ga = A + (size_t)(m0 + row) * K + k0 + gchunk * 8;
      const bf16* gb = B + (size_t)(n0 + row) * K + k0 + gchunk * 8;
      __builtin_amdgcn_global_load_lds((const AS1 void*)ga, (AS3 void*)(Asl + buf * 4096 + c * 512), 16, 0, 0);
      __builtin_amdgcn_global_load_lds((const AS1 void*)gb, (AS3 void*)(Bsl + buf * 4096 + c * 512), 16, 0, 0);
    }
  };

  const int nk = K >> 5;
  stage(0, 0);
  for (int it = 0; it < nk; ++it) {
    __syncthreads();
    if (it + 1 < nk) stage((it + 1) & 1, (it + 1) << 5);
    const bf16* As = Asl + (it & 1) * 4096;
    const bf16* Bs = Bsl + (it & 1) * 4096;

    bf16x8 af[4], bfr[4];
#pragma unroll
    for (int i = 0; i < 4; ++i) {
      const int r = wr * 64 + i * 16 + col;
      af[i] = *(const bf16x8*)&As[r * 32 + ((quad ^ (col & 3)) * 8)];
    }
#pragma unroll
    for (int j = 0; j < 4; ++j) {
      const int r = wc * 64 + j * 16 + col;
      bfr[j] = *(const bf16x8*)&Bs[r * 32 + ((quad ^ (col & 3)) * 8)];
    }
#pragma unroll
    for (int i = 0; i < 4; ++i)
#pragma unroll
      for (int j = 0; j < 4; ++j)
        acc[i][j] = __builtin_amdgcn_mfma_f32_16x16x32_bf16(af[i], bfr[j], acc[i][j], 0, 0, 0);
  }

#pragma unroll
  for (int i = 0; i < 4; ++i) {
#pragma unroll
    for (int j = 0; j < 4; ++j) {
      const int gm0 = m0 + wr * 64 + i * 16 + quad * 4;
      const int gn  = n0 + wc * 64 + j * 16 + col;
      if (OUTF32) {
#pragma unroll
        for (int r = 0; r < 4; ++r)
          Cf[(size_t)(gm0 + r) * N + gn] = acc[i][j][r] * scale;
      } else if (vtr) {
        bf16x4 ob;
#pragma unroll
        for (int r = 0; r < 4; ++r) ob[r] = (bf16)(acc[i][j][r] * scale);
        const int bb = gm0 >> 11;        // m = bb*2048 + t
        const int t_ = gm0 & 2047;
        *(bf16x4*)&Cb[((size_t)(bb * 1024 + gn)) * 2048 + t_] = ob;
      } else {
#pragma unroll
        for (int r = 0; r < 4; ++r)
          Cb[(size_t)(gm0 + r) * N + gn] = (bf16)(acc[i][j][r] * scale);
      }
    }
  }
}

// fused Q/K/V projection: blockIdx.z selects weight/output; z==2 (V) stores
// directly transposed into Vt (kills the separate transpose_v dispatch).
__global__ __launch_bounds__(256, 2)
void gemm_qkv(const bf16* __restrict__ A, const bf16* __restrict__ Wq,
              const bf16* __restrict__ Wk, const bf16* __restrict__ Wv,
              bf16* Qo, bf16* Ko, bf16* Vto, float qscale) {
  __shared__ bf16 Asl[2 * 4096];
  __shared__ bf16 Bsl[2 * 4096];
  const bf16* B; bf16* C; float sc = 1.0f; int vtr = 0;
  if (blockIdx.z == 0)      { B = Wq; C = Qo; sc = qscale; }
  else if (blockIdx.z == 1) { B = Wk; C = Ko; }
  else                      { B = Wv; C = Vto; vtr = 1; }
  gemm_body<0>(A, B, nullptr, C, 8192, 1024, 1024, sc, Asl, Bsl, vtr);
}

__global__ __launch_bounds__(256, 2)
void gemm_o(const bf16* __restrict__ A, const bf16* __restrict__ W, float* __restrict__ C) {
  __shared__ bf16 Asl[2 * 4096];
  __shared__ bf16 Bsl[2 * 4096];
  gemm_body<1>(A, W, C, nullptr, 8192, 1024, 1024, 1.0f, Asl, Bsl, 0);
}

// ---------------- flash causal attention, S^T, 8 waves x 1 q-strip ----------------
// Q pre-scaled by 0.125*log2(e). Vt: [(b*1024+n), t].
// R9: K OUT OF LDS. R8's counters showed the LDS pipe saturated: each of the
// 16 waves/CU re-read the whole 8KB K + 8KB V tile from LDS per iter
// (256KB/CU/iter > ~85B/cyc DS rate) and conflicts doubled to 9.1M cyc.
// Fix: K fragments load straight from global/L2 (swizzle cancels: chunk==quad;
// K per (b,h)=256KB is L2-resident, 8 blocks share it). 1-iter register
// double-buffer (kA/kB, static indexing via explicit 2x-unrolled loop body --
// ntt is always even) hides L2/HBM latency under softmax+PV. LDS now stages
// V only (16KB dbuf); staging + vmcnt drain halved. Epilogue stores O^T
// directly to global (bf16x4; L2 write-combines) -- no LDS transpose.
// Keeps R7 pairing (block p: qt=15-p then qt=p) and R8 8-wave blocks.
__global__ __launch_bounds__(512, 4)
void attn_flash(const bf16* __restrict__ Q, const bf16* __restrict__ K,
                const bf16* __restrict__ Vt, bf16* __restrict__ Y) {
  __shared__ bf16 Vsb[2][64 * 64];   // 16KB: V double-buffer only

  const int tid  = threadIdx.x;
  const int lane = tid & 63, wave = tid >> 6;   // wave 0..7
  const int quad = lane >> 4, col = lane & 15;
  const int p  = blockIdx.x;   // 0..7 (pair index)
  const int h  = blockIdx.y;
  const int b  = blockIdx.z;
  const int hc = h * 64;
  const size_t rowBase = (size_t)b * SQLEN;

  const int srow8 = lane >> 3;
  const int sch   = lane & 7;
  const int gch   = sch ^ srow8;   // XOR-8 swizzled global chunk (V staging)
  const int a7    = col & 7;

  const bf16* Kbh = K + rowBase * EMB + hc;   // K row t -> Kbh + t*EMB

  auto stageV = [&](int buf, int t0) {
    const int rr = wave * 8 + srow8;           // 8 waves x 8 rows = 64 V rows
    const bf16* gv = Vt + ((size_t)(b * EMB + hc + rr)) * SQLEN + t0 + gch * 8;
    __builtin_amdgcn_global_load_lds((const AS1 void*)gv, (AS3 void*)(&Vsb[buf][wave * 512]), 16, 0, 0);
  };

  // K fragments for a 64-key tile, straight from global (16B loads, 16 rows
  // per sl x 64B+64B halves -> 4 lanes per 64B line, fully coalesced).
  auto loadK = [&](bf16x8 (&k0)[4], bf16x8 (&k1)[4], int t0) {
#pragma unroll
    for (int sl = 0; sl < 4; ++sl) {
      const bf16* gk = Kbh + (size_t)(t0 + sl * 16 + col) * EMB + quad * 8;
      k0[sl] = *(const bf16x8*)gk;
      k1[sl] = *(const bf16x8*)(gk + 32);
    }
  };

  for (int halfIdx = 0; halfIdx < 2; ++halfIdx) {
    const int qt = halfIdx == 0 ? (15 - p) : p;  // paired: ntt sums to 34
    const int q0 = qt * 128;
    const int ntt = 2 * qt + 2;                  // always even

    bf16x8 kA0[4], kA1[4], kB0[4], kB1[4];
    loadK(kA0, kA1, 0);
    stageV(0, 0);

    // Wave's strip: q = q0 + wave*16 + col. 16x16x32 B-frag needs
    // k = quad*8..+7 (frag0) and 32+quad*8..+7 (frag1).
    bf16x8 qf0, qf1;
    {
      const int row = wave * 16 + col;
      const bf16* gq = Q + (rowBase + q0 + row) * EMB + hc + quad * 8;
      qf0 = *(const bf16x8*)gq;
      qf1 = *(const bf16x8*)(gq + 32);
    }
    __syncthreads();   // V tile 0 staged (barrier drains vmcnt -> K/Q regs too)

    float m_i = -INFINITY, l_i = 0.f;
    f32x4 o[4];
    const f32x4 fz = {0.f, 0.f, 0.f, 0.f};
#pragma unroll
    for (int dd = 0; dd < 4; ++dd) o[dd] = fz;

    // One 64-key iteration. cur K frags by const ref; prefetches next tile's
    // K into (n0,n1) AFTER QK^T consumed cur (keeps peak VGPR ~1 set + 1 in
    // flight; loads hide under softmax+PV+barrier ~2000cyc >> HBM 900cyc).
    auto iterBody = [&](const bf16x8 (&c0)[4], const bf16x8 (&c1)[4],
                        bf16x8 (&n0)[4], bf16x8 (&n1)[4], int tt) {
      const int t0 = tt * 64;
      const int cur = tt & 1;
      if (tt + 1 < ntt) stageV(cur ^ 1, t0 + 64);
      const bf16* Vs = &Vsb[cur][0];

      // ---- S^T slab from register K frags ----
      f32x4 s[4];
      __builtin_amdgcn_s_setprio(1);
#pragma unroll
      for (int sl = 0; sl < 4; ++sl) {
        f32x4 z = fz;
        z = __builtin_amdgcn_mfma_f32_16x16x32_bf16(c0[sl], qf0, z, 0, 0, 0);
        s[sl] = __builtin_amdgcn_mfma_f32_16x16x32_bf16(c1[sl], qf1, z, 0, 0, 0);
      }
      __builtin_amdgcn_s_setprio(0);

      // prefetch next K tile into the spare register set
      if (tt + 1 < ntt) loadK(n0, n1, t0 + 64);

      if (tt >= 2 * qt) {  // diagonal region: global-index causal mask
        const int qg = q0 + wave * 16 + col;
#pragma unroll
        for (int sl = 0; sl < 4; ++sl)
#pragma unroll
          for (int r = 0; r < 4; ++r)
            if (t0 + sl * 16 + quad * 4 + r > qg) s[sl][r] = -INFINITY;
      }

      // ---- online softmax (T13 defer-rescale, THR=8 in log2 domain) ----
      bf16x4 pb[4];
      {
        float mx = s[0][0];
#pragma unroll
        for (int sl = 0; sl < 4; ++sl)
#pragma unroll
          for (int r = 0; r < 4; ++r) mx = fmaxf(mx, s[sl][r]);
        mx = fmaxf(mx, __shfl_xor(mx, 16));
        mx = fmaxf(mx, __shfl_xor(mx, 32));
        if (!__all(mx <= m_i + 8.f)) {   // rescale only on real max growth
          const float mnew = fmaxf(m_i, mx);
          const float a = __builtin_amdgcn_exp2f(m_i - mnew);
          l_i *= a;
#pragma unroll
          for (int dd = 0; dd < 4; ++dd) o[dd] *= a;
          m_i = mnew;
        }
        float rs = 0.f;
#pragma unroll
        for (int sl = 0; sl < 4; ++sl)
#pragma unroll
          for (int r = 0; r < 4; ++r) {
            const float pv = __builtin_amdgcn_exp2f(s[sl][r] - m_i);  // <= 2^8
            rs += pv;
            pb[sl][r] = (bf16)pv;
          }
        rs += __shfl_xor(rs, 16);
        rs += __shfl_xor(rs, 32);
        l_i += rs;
      }

      // ---- O^T += V^T P^T (V from LDS, XOR-swizzled) ----
      __builtin_amdgcn_s_setprio(1);
#pragma unroll
      for (int sl = 0; sl < 4; ++sl) {
        const s16x4 pf = __builtin_bit_cast(s16x4, pb[sl]);
        const int cch  = 2 * sl + (quad >> 1);
        const int half = quad & 1;
#pragma unroll
        for (int dd = 0; dd < 4; ++dd) {
          const int row = dd * 16 + col;
          const bf16x4 vb = *(const bf16x4*)&Vs[row * 64 + ((cch ^ a7) * 8) + half * 4];
          const s16x4 vf = __builtin_bit_cast(s16x4, vb);
          o[dd] = __builtin_amdgcn_mfma_f32_16x16x16bf16_1k(vf, pf, o[dd], 0, 0, 0);
        }
      }
      __builtin_amdgcn_s_setprio(0);
      __syncthreads();  // drains V prefetch; guards dbuf reuse
    };

    for (int tt = 0; tt < ntt; tt += 2) {   // ntt even: static A/B alternation
      iterBody(kA0, kA1, kB0, kB1, tt);
      iterBody(kB0, kB1, kA0, kA1, tt + 1);
    }

    // ---- epilogue: O^T/l straight to global (bf16x4; L2 merges lines) ----
    {
      const float rl = __builtin_amdgcn_rcpf(l_i);
      const size_t yrow = (rowBase + q0 + wave * 16 + col) * EMB + hc;
#pragma unroll
      for (int dd = 0; dd < 4; ++dd) {
        bf16x4 ob;
#pragma unroll
        for (int r = 0; r < 4; ++r) ob[r] = (bf16)(o[dd][r] * rl);
        *(bf16x4*)&Y[yrow + dd * 16 + quad * 4] = ob;
      }
    }
    // no LDS use in epilogue; next half's stageV(0,0) is safe after the
    // final iter's barrier.
  }
}

// ---------------- launcher ----------------
extern "C" void kernel_launch(void* const* d_in, const int* in_sizes, int n_in,
                              void* d_out, int out_size, void* d_ws, size_t ws_size,
                              hipStream_t stream) {
  const float* x  = (const float*)d_in[0];
  const float* Wq = (const float*)d_in[1];
  const float* Wk = (const float*)d_in[2];
  const float* Wv = (const float*)d_in[3];
  const float* Wo = (const float*)d_in[4];
  float* out = (float*)d_out;

  const size_t ME = 8192ull * 1024ull;
  const size_t WE = 1024ull * 1024ull;
  bf16* ws  = (bf16*)d_ws;
  bf16* xb  = ws;
  bf16* wqb = xb + ME;
  bf16* wkb = wqb + WE;
  bf16* wvb = wkb + WE;
  bf16* wob = wvb + WE;
  bf16* Qb  = wob + WE;
  bf16* Kb  = Qb + ME;
  bf16* Vtb = Kb + ME;   // V written directly transposed by gemm_qkv (z==2)
  bf16* Yb  = Vtb + ME;

  cvt_f32_bf16<<<(int)(ME / 8 / 256), 256, 0, stream>>>(x, xb, (int)(ME / 8));
  cvt_w4<<<dim3((int)(WE / 8 / 256), 4), 256, 0, stream>>>(Wq, Wk, Wv, Wo, wqb, wkb, wvb, wob, (int)(WE / 8));

  const float qscale = 0.125f * 1.4426950408889634f;
  gemm_qkv<<<dim3(64, 8, 3), 256, 0, stream>>>(xb, wqb, wkb, wvb, Qb, Kb, Vtb, qscale);

  attn_flash<<<dim3(8, 16, 4), 512, 0, stream>>>(Qb, Kb, Vtb, Yb);

  gemm_o<<<dim3(64, 8), 256, 0, stream>>>(Yb, wob, out);
}

// Round 6
// 319.916 us; speedup vs baseline: 1.0614x; 1.0614x over previous
//
#include <hip/hip_runtime.h>

typedef __bf16 bf16;
typedef bf16  bf16x8 __attribute__((ext_vector_type(8)));
typedef bf16  bf16x4 __attribute__((ext_vector_type(4)));
typedef short s16x4  __attribute__((ext_vector_type(4)));
typedef float f32x4  __attribute__((ext_vector_type(4)));

#define AS1 __attribute__((address_space(1)))
#define AS3 __attribute__((address_space(3)))

#define SQLEN 2048
#define EMB   1024

// ---------------- fp32 -> bf16 convert (memory-bound) ----------------
__global__ __launch_bounds__(256) void cvt_f32_bf16(const float* __restrict__ in,
                                                    bf16* __restrict__ out, int n8) {
  int i = blockIdx.x * blockDim.x + threadIdx.x;
  if (i >= n8) return;
  const float4* p = (const float4*)in + (size_t)i * 2;
  float4 a = p[0], b = p[1];
  bf16x8 o;
  o[0] = (bf16)a.x; o[1] = (bf16)a.y; o[2] = (bf16)a.z; o[3] = (bf16)a.w;
  o[4] = (bf16)b.x; o[5] = (bf16)b.y; o[6] = (bf16)b.z; o[7] = (bf16)b.w;
  *((bf16x8*)out + i) = o;
}

// 4 weight matrices in one dispatch (blockIdx.y selects)
__global__ __launch_bounds__(256) void cvt_w4(const float* __restrict__ w0, const float* __restrict__ w1,
                                              const float* __restrict__ w2, const float* __restrict__ w3,
                                              bf16* o0, bf16* o1, bf16* o2, bf16* o3, int n8) {
  const float* in; bf16* out;
  switch (blockIdx.y) {
    case 0: in = w0; out = o0; break;
    case 1: in = w1; out = o1; break;
    case 2: in = w2; out = o2; break;
    default: in = w3; out = o3; break;
  }
  int i = blockIdx.x * blockDim.x + threadIdx.x;
  if (i >= n8) return;
  const float4* p = (const float4*)in + (size_t)i * 2;
  float4 a = p[0], b = p[1];
  bf16x8 o;
  o[0] = (bf16)a.x; o[1] = (bf16)a.y; o[2] = (bf16)a.z; o[3] = (bf16)a.w;
  o[4] = (bf16)b.x; o[5] = (bf16)b.y; o[6] = (bf16)b.z; o[7] = (bf16)b.w;
  *((bf16x8*)out + i) = o;
}

// ---------------- NT GEMM body: C[M,N] = A[M,K]*B[N,K]^T, dbuf single-barrier K-loop
// vtr (runtime, only bf16 path): store transposed as Vt[(b*1024+n)][t] where
// m = b*2048 + t. Each lane's 4 acc rows are 4 consecutive t at fixed n -> one
// bf16x4 store; 4 quads of a col form a 32B run per Vt row.
template <int OUTF32>
__device__ __forceinline__
void gemm_body(const bf16* __restrict__ A, const bf16* __restrict__ B,
               float* __restrict__ Cf, bf16* __restrict__ Cb,
               int M, int N, int K, float scale, bf16* Asl, bf16* Bsl, int vtr) {
  const int tid  = threadIdx.x;
  const int lane = tid & 63, wave = tid >> 6;
  const int quad = lane >> 4, col = lane & 15;
  const int m0 = blockIdx.x * 128, n0 = blockIdx.y * 128;
  const int wr = wave >> 1, wc = wave & 1;

  f32x4 acc[4][4];
  const f32x4 fz = {0.f, 0.f, 0.f, 0.f};
#pragma unroll
  for (int i = 0; i < 4; ++i)
#pragma unroll
    for (int j = 0; j < 4; ++j) acc[i][j] = fz;

  const int srow = lane >> 2;
  const int sk   = lane & 3;

  auto stage = [&](int buf, int k0) {
#pragma unroll
    for (int r = 0; r < 2; ++r) {
      const int c      = wave * 2 + r;
      const int row    = c * 16 + srow;
      const int gchunk = sk ^ (row & 3);
      const bf16* ga = A + (size_t)(m0 + row) * K + k0 + gchunk * 8;
      const bf16* gb = B + (size_t)(n0 + row) * K + k0 + gchunk * 8;
      __builtin_amdgcn_global_load_lds((const AS1 void*)ga, (AS3 void*)(Asl + buf * 4096 + c * 512), 16, 0, 0);
      __builtin_amdgcn_global_load_lds((const AS1 void*)gb, (AS3 void*)(Bsl + buf * 4096 + c * 512), 16, 0, 0);
    }
  };

  const int nk = K >> 5;
  stage(0, 0);
  for (int it = 0; it < nk; ++it) {
    __syncthreads();
    if (it + 1 < nk) stage((it + 1) & 1, (it + 1) << 5);
    const bf16* As = Asl + (it & 1) * 4096;
    const bf16* Bs = Bsl + (it & 1) * 4096;

    bf16x8 af[4], bfr[4];
#pragma unroll
    for (int i = 0; i < 4; ++i) {
      const int r = wr * 64 + i * 16 + col;
      af[i] = *(const bf16x8*)&As[r * 32 + ((quad ^ (col & 3)) * 8)];
    }
#pragma unroll
    for (int j = 0; j < 4; ++j) {
      const int r = wc * 64 + j * 16 + col;
      bfr[j] = *(const bf16x8*)&Bs[r * 32 + ((quad ^ (col & 3)) * 8)];
    }
#pragma unroll
    for (int i = 0; i < 4; ++i)
#pragma unroll
      for (int j = 0; j < 4; ++j)
        acc[i][j] = __builtin_amdgcn_mfma_f32_16x16x32_bf16(af[i], bfr[j], acc[i][j], 0, 0, 0);
  }

#pragma unroll
  for (int i = 0; i < 4; ++i) {
#pragma unroll
    for (int j = 0; j < 4; ++j) {
      const int gm0 = m0 + wr * 64 + i * 16 + quad * 4;
      const int gn  = n0 + wc * 64 + j * 16 + col;
      if (OUTF32) {
#pragma unroll
        for (int r = 0; r < 4; ++r)
          Cf[(size_t)(gm0 + r) * N + gn] = acc[i][j][r] * scale;
      } else if (vtr) {
        bf16x4 ob;
#pragma unroll
        for (int r = 0; r < 4; ++r) ob[r] = (bf16)(acc[i][j][r] * scale);
        const int bb = gm0 >> 11;        // m = bb*2048 + t
        const int t_ = gm0 & 2047;
        *(bf16x4*)&Cb[((size_t)(bb * 1024 + gn)) * 2048 + t_] = ob;
      } else {
#pragma unroll
        for (int r = 0; r < 4; ++r)
          Cb[(size_t)(gm0 + r) * N + gn] = (bf16)(acc[i][j][r] * scale);
      }
    }
  }
}

// fused Q/K/V projection: blockIdx.z selects weight/output; z==2 (V) stores
// directly transposed into Vt (kills the separate transpose_v dispatch).
__global__ __launch_bounds__(256, 2)
void gemm_qkv(const bf16* __restrict__ A, const bf16* __restrict__ Wq,
              const bf16* __restrict__ Wk, const bf16* __restrict__ Wv,
              bf16* Qo, bf16* Ko, bf16* Vto, float qscale) {
  __shared__ bf16 Asl[2 * 4096];
  __shared__ bf16 Bsl[2 * 4096];
  const bf16* B; bf16* C; float sc = 1.0f; int vtr = 0;
  if (blockIdx.z == 0)      { B = Wq; C = Qo; sc = qscale; }
  else if (blockIdx.z == 1) { B = Wk; C = Ko; }
  else                      { B = Wv; C = Vto; vtr = 1; }
  gemm_body<0>(A, B, nullptr, C, 8192, 1024, 1024, sc, Asl, Bsl, vtr);
}

__global__ __launch_bounds__(256, 2)
void gemm_o(const bf16* __restrict__ A, const bf16* __restrict__ W, float* __restrict__ C) {
  __shared__ bf16 Asl[2 * 4096];
  __shared__ bf16 Bsl[2 * 4096];
  gemm_body<1>(A, W, C, nullptr, 8192, 1024, 1024, 1.0f, Asl, Bsl, 0);
}

// ---------------- flash causal attention, S^T, 8 waves x 1 q-strip ----------------
// Q pre-scaled by 0.125*log2(e). Vt: [(b*1024+n), t].
// R10: K from global as TRANSIENTS (no cross-iter register state).
// R8 showed the LDS pipe saturated (~75% busy: 16KB LDS reads/wave-iter x 16
// waves/CU vs 128B/cyc). R9 moved K to a register double-buffer and the
// 4 persistent arrays got scratch-allocated (WRITE_SIZE 16K->60MB) -> 2x
// regression. Fix: load the 8 K fragments fresh each iteration straight from
// global, consumed immediately. All 8 waves of a block read the SAME 8KB K
// tile -> L1-resident; K per (b,h)=256KB shared by 8 blocks -> L2-resident.
// Exposed latency ~50-200cyc/iter hidden by 16 waves/CU. LDS stages V only
// (16KB dbuf, traffic halved); epilogue stores O^T straight to global.
// Keeps R7 pairing (block p: qt=15-p then qt=p) and R8 8-wave blocks.
__global__ __launch_bounds__(512, 4)
void attn_flash(const bf16* __restrict__ Q, const bf16* __restrict__ K,
                const bf16* __restrict__ Vt, bf16* __restrict__ Y) {
  __shared__ bf16 Vsb[2][64 * 64];   // 16KB: V double-buffer only

  const int tid  = threadIdx.x;
  const int lane = tid & 63, wave = tid >> 6;   // wave 0..7
  const int quad = lane >> 4, col = lane & 15;
  const int p  = blockIdx.x;   // 0..7 (pair index)
  const int h  = blockIdx.y;
  const int b  = blockIdx.z;
  const int hc = h * 64;
  const size_t rowBase = (size_t)b * SQLEN;

  const int srow8 = lane >> 3;
  const int sch   = lane & 7;
  const int gch   = sch ^ srow8;   // XOR-8 swizzled global chunk (V staging)
  const int a7    = col & 7;

  const bf16* Kbh = K + rowBase * EMB + hc;   // K row t -> Kbh + t*EMB

  auto stageV = [&](int buf, int t0) {
    const int rr = wave * 8 + srow8;           // 8 waves x 8 rows = 64 V rows
    const bf16* gv = Vt + ((size_t)(b * EMB + hc + rr)) * SQLEN + t0 + gch * 8;
    __builtin_amdgcn_global_load_lds((const AS1 void*)gv, (AS3 void*)(&Vsb[buf][wave * 512]), 16, 0, 0);
  };

  for (int halfIdx = 0; halfIdx < 2; ++halfIdx) {
    const int qt = halfIdx == 0 ? (15 - p) : p;  // paired: ntt sums to 34
    const int q0 = qt * 128;
    const int ntt = 2 * qt + 2;

    stageV(0, 0);

    // Wave's strip: q = q0 + wave*16 + col. 16x16x32 B-frag needs
    // k = quad*8..+7 (frag0) and 32+quad*8..+7 (frag1).
    bf16x8 qf0, qf1;
    {
      const int row = wave * 16 + col;
      const bf16* gq = Q + (rowBase + q0 + row) * EMB + hc + quad * 8;
      qf0 = *(const bf16x8*)gq;
      qf1 = *(const bf16x8*)(gq + 32);
    }
    __syncthreads();   // V tile 0 staged

    float m_i = -INFINITY, l_i = 0.f;
    f32x4 o[4];
    const f32x4 fz = {0.f, 0.f, 0.f, 0.f};
#pragma unroll
    for (int dd = 0; dd < 4; ++dd) o[dd] = fz;

    for (int tt = 0; tt < ntt; ++tt) {
      const int t0 = tt * 64;
      const int cur = tt & 1;
      if (tt + 1 < ntt) stageV(cur ^ 1, t0 + 64);  // V prefetch in flight
      const bf16* Vs = &Vsb[cur][0];

      // ---- K fragments straight from global/L1 (transient; 8x b128) ----
      // 16 rows per sl; 4 lanes share each 64B line half -> fully coalesced.
      bf16x8 kf0[4], kf1[4];
#pragma unroll
      for (int sl = 0; sl < 4; ++sl) {
        const bf16* gk = Kbh + (size_t)(t0 + sl * 16 + col) * EMB + quad * 8;
        kf0[sl] = *(const bf16x8*)gk;
        kf1[sl] = *(const bf16x8*)(gk + 32);
      }

      // ---- S^T slab ----
      f32x4 s[4];
      __builtin_amdgcn_s_setprio(1);
#pragma unroll
      for (int sl = 0; sl < 4; ++sl) {
        f32x4 z = fz;
        z = __builtin_amdgcn_mfma_f32_16x16x32_bf16(kf0[sl], qf0, z, 0, 0, 0);
        s[sl] = __builtin_amdgcn_mfma_f32_16x16x32_bf16(kf1[sl], qf1, z, 0, 0, 0);
      }
      __builtin_amdgcn_s_setprio(0);

      if (tt >= 2 * qt) {  // diagonal region: global-index causal mask
        const int qg = q0 + wave * 16 + col;
#pragma unroll
        for (int sl = 0; sl < 4; ++sl)
#pragma unroll
          for (int r = 0; r < 4; ++r)
            if (t0 + sl * 16 + quad * 4 + r > qg) s[sl][r] = -INFINITY;
      }

      // ---- online softmax (T13 defer-rescale, THR=8 in log2 domain) ----
      bf16x4 pb[4];
      {
        float mx = s[0][0];
#pragma unroll
        for (int sl = 0; sl < 4; ++sl)
#pragma unroll
          for (int r = 0; r < 4; ++r) mx = fmaxf(mx, s[sl][r]);
        mx = fmaxf(mx, __shfl_xor(mx, 16));
        mx = fmaxf(mx, __shfl_xor(mx, 32));
        if (!__all(mx <= m_i + 8.f)) {   // rescale only on real max growth
          const float mnew = fmaxf(m_i, mx);
          const float a = __builtin_amdgcn_exp2f(m_i - mnew);
          l_i *= a;
#pragma unroll
          for (int dd = 0; dd < 4; ++dd) o[dd] *= a;
          m_i = mnew;
        }
        float rs = 0.f;
#pragma unroll
        for (int sl = 0; sl < 4; ++sl)
#pragma unroll
          for (int r = 0; r < 4; ++r) {
            const float pv = __builtin_amdgcn_exp2f(s[sl][r] - m_i);  // <= 2^8
            rs += pv;
            pb[sl][r] = (bf16)pv;
          }
        rs += __shfl_xor(rs, 16);
        rs += __shfl_xor(rs, 32);
        l_i += rs;
      }

      // ---- O^T += V^T P^T (V from LDS, XOR-swizzled) ----
      __builtin_amdgcn_s_setprio(1);
#pragma unroll
      for (int sl = 0; sl < 4; ++sl) {
        const s16x4 pf = __builtin_bit_cast(s16x4, pb[sl]);
        const int cch  = 2 * sl + (quad >> 1);
        const int half = quad & 1;
#pragma unroll
        for (int dd = 0; dd < 4; ++dd) {
          const int row = dd * 16 + col;
          const bf16x4 vb = *(const bf16x4*)&Vs[row * 64 + ((cch ^ a7) * 8) + half * 4];
          const s16x4 vf = __builtin_bit_cast(s16x4, vb);
          o[dd] = __builtin_amdgcn_mfma_f32_16x16x16bf16_1k(vf, pf, o[dd], 0, 0, 0);
        }
      }
      __builtin_amdgcn_s_setprio(0);
      __syncthreads();  // drains V prefetch; guards dbuf reuse
    }

    // ---- epilogue: O^T/l straight to global (bf16x4; L2 merges lines) ----
    {
      const float rl = __builtin_amdgcn_rcpf(l_i);
      const size_t yrow = (rowBase + q0 + wave * 16 + col) * EMB + hc;
#pragma unroll
      for (int dd = 0; dd < 4; ++dd) {
        bf16x4 ob;
#pragma unroll
        for (int r = 0; r < 4; ++r) ob[r] = (bf16)(o[dd][r] * rl);
        *(bf16x4*)&Y[yrow + dd * 16 + quad * 4] = ob;
      }
    }
    // no LDS use in epilogue; next half's stageV(0,0) is safe after the
    // final iter's barrier.
  }
}

// ---------------- launcher ----------------
extern "C" void kernel_launch(void* const* d_in, const int* in_sizes, int n_in,
                              void* d_out, int out_size, void* d_ws, size_t ws_size,
                              hipStream_t stream) {
  const float* x  = (const float*)d_in[0];
  const float* Wq = (const float*)d_in[1];
  const float* Wk = (const float*)d_in[2];
  const float* Wv = (const float*)d_in[3];
  const float* Wo = (const float*)d_in[4];
  float* out = (float*)d_out;

  const size_t ME = 8192ull * 1024ull;
  const size_t WE = 1024ull * 1024ull;
  bf16* ws  = (bf16*)d_ws;
  bf16* xb  = ws;
  bf16* wqb = xb + ME;
  bf16* wkb = wqb + WE;
  bf16* wvb = wkb + WE;
  bf16* wob = wvb + WE;
  bf16* Qb  = wob + WE;
  bf16* Kb  = Qb + ME;
  bf16* Vtb = Kb + ME;   // V written directly transposed by gemm_qkv (z==2)
  bf16* Yb  = Vtb + ME;

  cvt_f32_bf16<<<(int)(ME / 8 / 256), 256, 0, stream>>>(x, xb, (int)(ME / 8));
  cvt_w4<<<dim3((int)(WE / 8 / 256), 4), 256, 0, stream>>>(Wq, Wk, Wv, Wo, wqb, wkb, wvb, wob, (int)(WE / 8));

  const float qscale = 0.125f * 1.4426950408889634f;
  gemm_qkv<<<dim3(64, 8, 3), 256, 0, stream>>>(xb, wqb, wkb, wvb, Qb, Kb, Vtb, qscale);

  attn_flash<<<dim3(8, 16, 4), 512, 0, stream>>>(Qb, Kb, Vtb, Yb);

  gemm_o<<<dim3(64, 8), 256, 0, stream>>>(Yb, wob, out);
}

// Round 8
// 251.396 us; speedup vs baseline: 1.3507x; 1.2726x over previous
//
#include <hip/hip_runtime.h>

typedef __bf16 bf16;
typedef bf16  bf16x8 __attribute__((ext_vector_type(8)));
typedef bf16  bf16x4 __attribute__((ext_vector_type(4)));
typedef short s16x4  __attribute__((ext_vector_type(4)));
typedef float f32x4  __attribute__((ext_vector_type(4)));

#define AS1 __attribute__((address_space(1)))
#define AS3 __attribute__((address_space(3)))

#define SQLEN 2048
#define EMB   1024

// ---------------- fp32 -> bf16 convert (memory-bound) ----------------
__global__ __launch_bounds__(256) void cvt_f32_bf16(const float* __restrict__ in,
                                                    bf16* __restrict__ out, int n8) {
  int i = blockIdx.x * blockDim.x + threadIdx.x;
  if (i >= n8) return;
  const float4* p = (const float4*)in + (size_t)i * 2;
  float4 a = p[0], b = p[1];
  bf16x8 o;
  o[0] = (bf16)a.x; o[1] = (bf16)a.y; o[2] = (bf16)a.z; o[3] = (bf16)a.w;
  o[4] = (bf16)b.x; o[5] = (bf16)b.y; o[6] = (bf16)b.z; o[7] = (bf16)b.w;
  *((bf16x8*)out + i) = o;
}

// 4 weight matrices in one dispatch (blockIdx.y selects)
__global__ __launch_bounds__(256) void cvt_w4(const float* __restrict__ w0, const float* __restrict__ w1,
                                              const float* __restrict__ w2, const float* __restrict__ w3,
                                              bf16* o0, bf16* o1, bf16* o2, bf16* o3, int n8) {
  const float* in; bf16* out;
  switch (blockIdx.y) {
    case 0: in = w0; out = o0; break;
    case 1: in = w1; out = o1; break;
    case 2: in = w2; out = o2; break;
    default: in = w3; out = o3; break;
  }
  int i = blockIdx.x * blockDim.x + threadIdx.x;
  if (i >= n8) return;
  const float4* p = (const float4*)in + (size_t)i * 2;
  float4 a = p[0], b = p[1];
  bf16x8 o;
  o[0] = (bf16)a.x; o[1] = (bf16)a.y; o[2] = (bf16)a.z; o[3] = (bf16)a.w;
  o[4] = (bf16)b.x; o[5] = (bf16)b.y; o[6] = (bf16)b.z; o[7] = (bf16)b.w;
  *((bf16x8*)out + i) = o;
}

// ---------------- NT GEMM body: C[M,N] = A[M,K]*B[N,K]^T, dbuf single-barrier K-loop
// vtr (runtime, only bf16 path): store transposed as Vt[(b*1024+n)][t] where
// m = b*2048 + t.
template <int OUTF32>
__device__ __forceinline__
void gemm_body(const bf16* __restrict__ A, const bf16* __restrict__ B,
               float* __restrict__ Cf, bf16* __restrict__ Cb,
               int M, int N, int K, float scale, bf16* Asl, bf16* Bsl, int vtr) {
  const int tid  = threadIdx.x;
  const int lane = tid & 63, wave = tid >> 6;
  const int quad = lane >> 4, col = lane & 15;
  const int m0 = blockIdx.x * 128, n0 = blockIdx.y * 128;
  const int wr = wave >> 1, wc = wave & 1;

  f32x4 acc[4][4];
  const f32x4 fz = {0.f, 0.f, 0.f, 0.f};
#pragma unroll
  for (int i = 0; i < 4; ++i)
#pragma unroll
    for (int j = 0; j < 4; ++j) acc[i][j] = fz;

  const int srow = lane >> 2;
  const int sk   = lane & 3;

  auto stage = [&](int buf, int k0) {
#pragma unroll
    for (int r = 0; r < 2; ++r) {
      const int c      = wave * 2 + r;
      const int row    = c * 16 + srow;
      const int gchunk = sk ^ (row & 3);
      const bf16* ga = A + (size_t)(m0 + row) * K + k0 + gchunk * 8;
      const bf16* gb = B + (size_t)(n0 + row) * K + k0 + gchunk * 8;
      __builtin_amdgcn_global_load_lds((const AS1 void*)ga, (AS3 void*)(Asl + buf * 4096 + c * 512), 16, 0, 0);
      __builtin_amdgcn_global_load_lds((const AS1 void*)gb, (AS3 void*)(Bsl + buf * 4096 + c * 512), 16, 0, 0);
    }
  };

  const int nk = K >> 5;
  stage(0, 0);
  for (int it = 0; it < nk; ++it) {
    __syncthreads();
    if (it + 1 < nk) stage((it + 1) & 1, (it + 1) << 5);
    const bf16* As = Asl + (it & 1) * 4096;
    const bf16* Bs = Bsl + (it & 1) * 4096;

    bf16x8 af[4], bfr[4];
#pragma unroll
    for (int i = 0; i < 4; ++i) {
      const int r = wr * 64 + i * 16 + col;
      af[i] = *(const bf16x8*)&As[r * 32 + ((quad ^ (col & 3)) * 8)];
    }
#pragma unroll
    for (int j = 0; j < 4; ++j) {
      const int r = wc * 64 + j * 16 + col;
      bfr[j] = *(const bf16x8*)&Bs[r * 32 + ((quad ^ (col & 3)) * 8)];
    }
#pragma unroll
    for (int i = 0; i < 4; ++i)
#pragma unroll
      for (int j = 0; j < 4; ++j)
        acc[i][j] = __builtin_amdgcn_mfma_f32_16x16x32_bf16(af[i], bfr[j], acc[i][j], 0, 0, 0);
  }

#pragma unroll
  for (int i = 0; i < 4; ++i) {
#pragma unroll
    for (int j = 0; j < 4; ++j) {
      const int gm0 = m0 + wr * 64 + i * 16 + quad * 4;
      const int gn  = n0 + wc * 64 + j * 16 + col;
      if (OUTF32) {
#pragma unroll
        for (int r = 0; r < 4; ++r)
          Cf[(size_t)(gm0 + r) * N + gn] = acc[i][j][r] * scale;
      } else if (vtr) {
        bf16x4 ob;
#pragma unroll
        for (int r = 0; r < 4; ++r) ob[r] = (bf16)(acc[i][j][r] * scale);
        const int bb = gm0 >> 11;        // m = bb*2048 + t
        const int t_ = gm0 & 2047;
        *(bf16x4*)&Cb[((size_t)(bb * 1024 + gn)) * 2048 + t_] = ob;
      } else {
#pragma unroll
        for (int r = 0; r < 4; ++r)
          Cb[(size_t)(gm0 + r) * N + gn] = (bf16)(acc[i][j][r] * scale);
      }
    }
  }
}

// fused Q/K/V projection: blockIdx.z selects weight/output; z==2 (V) stores
// directly transposed into Vt (kills the separate transpose_v dispatch).
__global__ __launch_bounds__(256, 2)
void gemm_qkv(const bf16* __restrict__ A, const bf16* __restrict__ Wq,
              const bf16* __restrict__ Wk, const bf16* __restrict__ Wv,
              bf16* Qo, bf16* Ko, bf16* Vto, float qscale) {
  __shared__ bf16 Asl[2 * 4096];
  __shared__ bf16 Bsl[2 * 4096];
  const bf16* B; bf16* C; float sc = 1.0f; int vtr = 0;
  if (blockIdx.z == 0)      { B = Wq; C = Qo; sc = qscale; }
  else if (blockIdx.z == 1) { B = Wk; C = Ko; }
  else                      { B = Wv; C = Vto; vtr = 1; }
  gemm_body<0>(A, B, nullptr, C, 8192, 1024, 1024, sc, Asl, Bsl, vtr);
}

__global__ __launch_bounds__(256, 2)
void gemm_o(const bf16* __restrict__ A, const bf16* __restrict__ W, float* __restrict__ C) {
  __shared__ bf16 Asl[2 * 4096];
  __shared__ bf16 Bsl[2 * 4096];
  gemm_body<1>(A, W, C, nullptr, 8192, 1024, 1024, 1.0f, Asl, Bsl, 0);
}

// ---------------- flash causal attention, S^T, 8 waves x 1 q-strip ----------------
// Q pre-scaled by 0.125*log2(e). Vt: [(b*1024+n), t].
// R12 = R11 resubmit (container infra failure, no counters) with one de-risk:
// stageKV's LDS dest is now the proven wave-uniform-base form (HW appends
// lane*16B itself; the previous +lane*8 per-lane pointer was arithmetically
// identical but an unverified idiom).
// R11 theory (on the R8 anchor, 78.4us): R9/R10 proved K must stay in LDS.
// R8's profile: no pipe saturated, wall/iter ~5500cyc vs ~2300 demand ->
// per-iter FIXED overhead dominates. So:
//  1. KVBLK=128: halves iters (34->17), barriers, shfl chains, staging issue.
//     LDS 64KB dbuf -> still exactly 2 blocks/CU (grid gives 2/CU).
//  2. l via ones-MFMA: denominator accumulated as mfma(ones,P) into f32x4,
//     rides the same defer-rescale as o; kills 32 adds + 2 serial shfl/iter
//     and the epilogue reduction.
//  3. XCD-grouped swizzle: 1D grid; all 8 pair-blocks of one (b,h) land on
//     one XCD (bid&7) -> 512KB K/V set L2-resident (8 bh x 512KB = 4MB L2).
// Keeps: R7 pairing (p: qt=15-p then qt=p), 8-wave blocks, T13 defer-rescale,
// T5 setprio, direct-to-global epilogue.
__global__ __launch_bounds__(512, 4)
void attn_flash(const bf16* __restrict__ Q, const bf16* __restrict__ K,
                const bf16* __restrict__ Vt, bf16* __restrict__ Y) {
  __shared__ bf16 Ksb0[2 * 8192];   // [buf][128 keys][64 d]   32KB
  __shared__ bf16 Vsb0[2 * 8192];   // [buf][64 d][128 t]      32KB

  const int tid  = threadIdx.x;
  const int lane = tid & 63, wave = tid >> 6;   // wave 0..7
  const int quad = lane >> 4, col = lane & 15;

  // XCD-grouped decode: XCD g = bid&7 handles bh in [g*8, g*8+8)
  const int B_ = blockIdx.x;            // 0..511
  const int bh = (B_ & 7) * 8 + (B_ >> 6);
  const int p  = (B_ >> 3) & 7;         // pair index 0..7
  const int h  = bh & 15;
  const int b  = bh >> 4;
  const int hc = h * 64;
  const size_t rowBase = (size_t)b * SQLEN;

  const int srow8 = lane >> 3;
  const int sch   = lane & 7;
  const int a7    = col & 7;

  // stage one 128-key K tile + matching V^T tile. LDS dest is wave-uniform;
  // HW writes lane l at dest + l*16B. Element order: lane l -> base + l*8 elems.
  // K: lane l covers row (wave*16 + i*8 + (l>>3)), chunk (l&7)^(l>>3)  [XOR-8]
  //    -> LDS elem idx = row*64 + (l&7)*8, i.e. Ks[row][sch], holding global
  //       chunk sch^(row&7).
  // V: lane l covers vrow (wave*8 + i*4 + (l>>4)), chunk (l&15)^(vrow&7)
  //    -> Vs[vrow][(l&15)*8], holding global chunk (l&15)^(vrow&7).
  auto stageKV = [&](int buf, int t0) {
#pragma unroll
    for (int i = 0; i < 2; ++i) {
      const int krow = wave * 16 + i * 8 + srow8;          // krow&7 == srow8
      const int kch  = sch ^ srow8;
      const bf16* gk = K + (rowBase + t0 + krow) * EMB + hc + kch * 8;
      __builtin_amdgcn_global_load_lds((const AS1 void*)gk,
          (AS3 void*)(Ksb0 + buf * 8192 + wave * 1024 + i * 512), 16, 0, 0);
      const int vrow = wave * 8 + i * 4 + (lane >> 4);
      const int vch  = (lane & 15) ^ (vrow & 7);
      const bf16* gv = Vt + ((size_t)(b * EMB + hc + vrow)) * SQLEN + t0 + vch * 8;
      __builtin_amdgcn_global_load_lds((const AS1 void*)gv,
          (AS3 void*)(Vsb0 + buf * 8192 + wave * 1024 + i * 512), 16, 0, 0);
    }
  };

  const s16x4 ones = {(short)0x3F80, (short)0x3F80, (short)0x3F80, (short)0x3F80};

  for (int halfIdx = 0; halfIdx < 2; ++halfIdx) {
    const int qt = halfIdx == 0 ? (15 - p) : p;  // paired: ntt sums to 17
    const int q0 = qt * 128;
    const int ntt = qt + 1;                      // 128-key tiles

    stageKV(0, 0);

    // Wave's strip: q = q0 + wave*16 + col. 16x16x32 B-frag needs
    // k = quad*8..+7 (frag0) and 32+quad*8..+7 (frag1).
    bf16x8 qf0, qf1;
    {
      const int row = wave * 16 + col;
      const bf16* gq = Q + (rowBase + q0 + row) * EMB + hc + quad * 8;
      qf0 = *(const bf16x8*)gq;
      qf1 = *(const bf16x8*)(gq + 32);
    }
    __syncthreads();   // K/V tile 0 staged

    float m_i = -INFINITY;
    f32x4 o[4], ol;
    const f32x4 fz = {0.f, 0.f, 0.f, 0.f};
#pragma unroll
    for (int dd = 0; dd < 4; ++dd) o[dd] = fz;
    ol = fz;

    for (int tt = 0; tt < ntt; ++tt) {
      const int t0 = tt * 128;
      const int cur = tt & 1;
      if (tt + 1 < ntt) stageKV(cur ^ 1, t0 + 128);  // prefetch in flight
      const bf16* Ks = Ksb0 + cur * 8192;
      const bf16* Vs = Vsb0 + cur * 8192;

      // ---- S^T: 8 slabs of 16 keys ----
      f32x4 s[8];
      __builtin_amdgcn_s_setprio(1);
#pragma unroll
      for (int sl = 0; sl < 8; ++sl) {
        const bf16x8 kf0 = *(const bf16x8*)&Ks[(sl * 16 + col) * 64 + ((quad ^ a7) * 8)];
        const bf16x8 kf1 = *(const bf16x8*)&Ks[(sl * 16 + col) * 64 + (((quad ^ 4) ^ a7) * 8)];
        f32x4 z = fz;
        z = __builtin_amdgcn_mfma_f32_16x16x32_bf16(kf0, qf0, z, 0, 0, 0);
        s[sl] = __builtin_amdgcn_mfma_f32_16x16x32_bf16(kf1, qf1, z, 0, 0, 0);
      }
      __builtin_amdgcn_s_setprio(0);

      if (tt == qt) {  // single diagonal tile: global-index causal mask
        const int qg = q0 + wave * 16 + col;
#pragma unroll
        for (int sl = 0; sl < 8; ++sl)
#pragma unroll
          for (int r = 0; r < 4; ++r)
            if (t0 + sl * 16 + quad * 4 + r > qg) s[sl][r] = -INFINITY;
      }

      // ---- online softmax (T13 defer-rescale, THR=8 in log2 domain);
      //      denominator accumulates via ones-MFMA below, no rs adds ----
      bf16x4 pb[8];
      {
        float mx = s[0][0];
#pragma unroll
        for (int sl = 0; sl < 8; ++sl)
#pragma unroll
          for (int r = 0; r < 4; ++r) mx = fmaxf(mx, s[sl][r]);
        mx = fmaxf(mx, __shfl_xor(mx, 16));
        mx = fmaxf(mx, __shfl_xor(mx, 32));
        if (!__all(mx <= m_i + 8.f)) {   // rescale only on real max growth
          const float mnew = fmaxf(m_i, mx);
          const float a = __builtin_amdgcn_exp2f(m_i - mnew);
#pragma unroll
          for (int dd = 0; dd < 4; ++dd) o[dd] *= a;
          ol *= a;
          m_i = mnew;
        }
#pragma unroll
        for (int sl = 0; sl < 8; ++sl)
#pragma unroll
          for (int r = 0; r < 4; ++r)
            pb[sl][r] = (bf16)__builtin_amdgcn_exp2f(s[sl][r] - m_i);  // <= 2^8
      }

      // ---- O^T += V^T P^T; l += 1^T P^T (ones-MFMA) ----
      __builtin_amdgcn_s_setprio(1);
#pragma unroll
      for (int sl = 0; sl < 8; ++sl) {
        const s16x4 pf = __builtin_bit_cast(s16x4, pb[sl]);
        ol = __builtin_amdgcn_mfma_f32_16x16x16bf16_1k(ones, pf, ol, 0, 0, 0);
        const int cch  = 2 * sl + (quad >> 1);   // 0..15
        const int half = quad & 1;
#pragma unroll
        for (int dd = 0; dd < 4; ++dd) {
          const int row = dd * 16 + col;
          const bf16x4 vb = *(const bf16x4*)&Vs[row * 128 + ((cch ^ a7) * 8) + half * 4];
          const s16x4 vf = __builtin_bit_cast(s16x4, vb);
          o[dd] = __builtin_amdgcn_mfma_f32_16x16x16bf16_1k(vf, pf, o[dd], 0, 0, 0);
        }
      }
      __builtin_amdgcn_s_setprio(0);
      __syncthreads();  // drains prefetch; guards dbuf reuse
    }

    // ---- epilogue: O^T/l straight to global (l replicated in every ol lane) ----
    {
      const float rl = __builtin_amdgcn_rcpf(ol[0]);
      const size_t yrow = (rowBase + q0 + wave * 16 + col) * EMB + hc;
#pragma unroll
      for (int dd = 0; dd < 4; ++dd) {
        bf16x4 ob;
#pragma unroll
        for (int r = 0; r < 4; ++r) ob[r] = (bf16)(o[dd][r] * rl);
        *(bf16x4*)&Y[yrow + dd * 16 + quad * 4] = ob;
      }
    }
    // epilogue is global-only; next half's stageKV(0,0) is safe after the
    // final iter's barrier.
  }
}

// ---------------- launcher ----------------
extern "C" void kernel_launch(void* const* d_in, const int* in_sizes, int n_in,
                              void* d_out, int out_size, void* d_ws, size_t ws_size,
                              hipStream_t stream) {
  const float* x  = (const float*)d_in[0];
  const float* Wq = (const float*)d_in[1];
  const float* Wk = (const float*)d_in[2];
  const float* Wv = (const float*)d_in[3];
  const float* Wo = (const float*)d_in[4];
  float* out = (float*)d_out;

  const size_t ME = 8192ull * 1024ull;
  const size_t WE = 1024ull * 1024ull;
  bf16* ws  = (bf16*)d_ws;
  bf16* xb  = ws;
  bf16* wqb = xb + ME;
  bf16* wkb = wqb + WE;
  bf16* wvb = wkb + WE;
  bf16* wob = wvb + WE;
  bf16* Qb  = wob + WE;
  bf16* Kb  = Qb + ME;
  bf16* Vtb = Kb + ME;   // V written directly transposed by gemm_qkv (z==2)
  bf16* Yb  = Vtb + ME;

  cvt_f32_bf16<<<(int)(ME / 8 / 256), 256, 0, stream>>>(x, xb, (int)(ME / 8));
  cvt_w4<<<dim3((int)(WE / 8 / 256), 4), 256, 0, stream>>>(Wq, Wk, Wv, Wo, wqb, wkb, wvb, wob, (int)(WE / 8));

  const float qscale = 0.125f * 1.4426950408889634f;
  gemm_qkv<<<dim3(64, 8, 3), 256, 0, stream>>>(xb, wqb, wkb, wvb, Qb, Kb, Vtb, qscale);

  attn_flash<<<512, 512, 0, stream>>>(Qb, Kb, Vtb, Yb);

  gemm_o<<<dim3(64, 8), 256, 0, stream>>>(Yb, wob, out);
}

// Round 9
// 240.495 us; speedup vs baseline: 1.4119x; 1.0453x over previous
//
#include <hip/hip_runtime.h>

typedef __bf16 bf16;
typedef bf16  bf16x8 __attribute__((ext_vector_type(8)));
typedef bf16  bf16x4 __attribute__((ext_vector_type(4)));
typedef short s16x4  __attribute__((ext_vector_type(4)));
typedef float f32x4  __attribute__((ext_vector_type(4)));

#define AS1 __attribute__((address_space(1)))
#define AS3 __attribute__((address_space(3)))

#define SQLEN 2048
#define EMB   1024

// ---------------- fp32 -> bf16 convert (memory-bound) ----------------
__global__ __launch_bounds__(256) void cvt_f32_bf16(const float* __restrict__ in,
                                                    bf16* __restrict__ out, int n8) {
  int i = blockIdx.x * blockDim.x + threadIdx.x;
  if (i >= n8) return;
  const float4* p = (const float4*)in + (size_t)i * 2;
  float4 a = p[0], b = p[1];
  bf16x8 o;
  o[0] = (bf16)a.x; o[1] = (bf16)a.y; o[2] = (bf16)a.z; o[3] = (bf16)a.w;
  o[4] = (bf16)b.x; o[5] = (bf16)b.y; o[6] = (bf16)b.z; o[7] = (bf16)b.w;
  *((bf16x8*)out + i) = o;
}

// 4 weight matrices in one dispatch (blockIdx.y selects)
__global__ __launch_bounds__(256) void cvt_w4(const float* __restrict__ w0, const float* __restrict__ w1,
                                              const float* __restrict__ w2, const float* __restrict__ w3,
                                              bf16* o0, bf16* o1, bf16* o2, bf16* o3, int n8) {
  const float* in; bf16* out;
  switch (blockIdx.y) {
    case 0: in = w0; out = o0; break;
    case 1: in = w1; out = o1; break;
    case 2: in = w2; out = o2; break;
    default: in = w3; out = o3; break;
  }
  int i = blockIdx.x * blockDim.x + threadIdx.x;
  if (i >= n8) return;
  const float4* p = (const float4*)in + (size_t)i * 2;
  float4 a = p[0], b = p[1];
  bf16x8 o;
  o[0] = (bf16)a.x; o[1] = (bf16)a.y; o[2] = (bf16)a.z; o[3] = (bf16)a.w;
  o[4] = (bf16)b.x; o[5] = (bf16)b.y; o[6] = (bf16)b.z; o[7] = (bf16)b.w;
  *((bf16x8*)out + i) = o;
}

// ---------------- NT GEMM body (used by gemm_o): C[M,N] = A*B^T, f32 out ----
__device__ __forceinline__
void gemm_body_f32(const bf16* __restrict__ A, const bf16* __restrict__ B,
                   float* __restrict__ Cf, int M, int N, int K,
                   bf16* Asl, bf16* Bsl) {
  const int tid  = threadIdx.x;
  const int lane = tid & 63, wave = tid >> 6;
  const int quad = lane >> 4, col = lane & 15;
  const int m0 = blockIdx.x * 128, n0 = blockIdx.y * 128;
  const int wr = wave >> 1, wc = wave & 1;

  f32x4 acc[4][4];
  const f32x4 fz = {0.f, 0.f, 0.f, 0.f};
#pragma unroll
  for (int i = 0; i < 4; ++i)
#pragma unroll
    for (int j = 0; j < 4; ++j) acc[i][j] = fz;

  const int srow = lane >> 2;
  const int sk   = lane & 3;

  auto stage = [&](int buf, int k0) {
#pragma unroll
    for (int r = 0; r < 2; ++r) {
      const int c      = wave * 2 + r;
      const int row    = c * 16 + srow;
      const int gchunk = sk ^ (row & 3);
      const bf16* ga = A + (size_t)(m0 + row) * K + k0 + gchunk * 8;
      const bf16* gb = B + (size_t)(n0 + row) * K + k0 + gchunk * 8;
      __builtin_amdgcn_global_load_lds((const AS1 void*)ga, (AS3 void*)(Asl + buf * 4096 + c * 512), 16, 0, 0);
      __builtin_amdgcn_global_load_lds((const AS1 void*)gb, (AS3 void*)(Bsl + buf * 4096 + c * 512), 16, 0, 0);
    }
  };

  const int nk = K >> 5;
  stage(0, 0);
  for (int it = 0; it < nk; ++it) {
    __syncthreads();
    if (it + 1 < nk) stage((it + 1) & 1, (it + 1) << 5);
    const bf16* As = Asl + (it & 1) * 4096;
    const bf16* Bs = Bsl + (it & 1) * 4096;

    bf16x8 af[4], bfr[4];
#pragma unroll
    for (int i = 0; i < 4; ++i) {
      const int r = wr * 64 + i * 16 + col;
      af[i] = *(const bf16x8*)&As[r * 32 + ((quad ^ (col & 3)) * 8)];
    }
#pragma unroll
    for (int j = 0; j < 4; ++j) {
      const int r = wc * 64 + j * 16 + col;
      bfr[j] = *(const bf16x8*)&Bs[r * 32 + ((quad ^ (col & 3)) * 8)];
    }
#pragma unroll
    for (int i = 0; i < 4; ++i)
#pragma unroll
      for (int j = 0; j < 4; ++j)
        acc[i][j] = __builtin_amdgcn_mfma_f32_16x16x32_bf16(af[i], bfr[j], acc[i][j], 0, 0, 0);
  }

#pragma unroll
  for (int i = 0; i < 4; ++i) {
#pragma unroll
    for (int j = 0; j < 4; ++j) {
      const int gm0 = m0 + wr * 64 + i * 16 + quad * 4;
      const int gn  = n0 + wc * 64 + j * 16 + col;
#pragma unroll
      for (int r = 0; r < 4; ++r)
        Cf[(size_t)(gm0 + r) * N + gn] = acc[i][j][r];
    }
  }
}

// ---------------- fused QKV GEMM: one block computes Q,K,V 128x128 tiles ----
// R13: the split-z gemm_qkv staged the SAME 128x32 A-tile 3x (once per z) and
// ran only 16 MFMA per barrier (MfmaUtil 28%, ~2150cyc/iter for 80cyc MFMA ->
// fixed overhead bound). Fused: stage A once + 3 B panels per K-iter, run
// 48 MFMA/wave/barrier. LDS 16+48=64KB -> 2 blocks/CU; acc 3x16 f32x4 =
// 192 AGPR + ~55 VGPR ~= 250 unified <= 256 cap @(256,2). Grid 64x8=512 =
// exactly one full round of 2/CU (old 1536-block grid ran 6 partial rounds).
// V (s==2) stores transposed into Vt[(b*1024+n)][t] (m = b*2048+t).
__global__ __launch_bounds__(256, 2)
void gemm_qkv(const bf16* __restrict__ A, const bf16* __restrict__ Wq,
              const bf16* __restrict__ Wk, const bf16* __restrict__ Wv,
              bf16* __restrict__ Qo, bf16* __restrict__ Ko, bf16* __restrict__ Vto,
              float qscale) {
  __shared__ bf16 Asl[2 * 4096];
  __shared__ bf16 Bsl[3][2 * 4096];

  const int tid  = threadIdx.x;
  const int lane = tid & 63, wave = tid >> 6;
  const int quad = lane >> 4, col = lane & 15;
  const int m0 = blockIdx.x * 128, n0 = blockIdx.y * 128;
  const int wr = wave >> 1, wc = wave & 1;
  const int K = 1024, N = 1024;

  const bf16* const Bp[3] = {Wq, Wk, Wv};

  f32x4 acc[3][4][4];
  const f32x4 fz = {0.f, 0.f, 0.f, 0.f};
#pragma unroll
  for (int s = 0; s < 3; ++s)
#pragma unroll
    for (int i = 0; i < 4; ++i)
#pragma unroll
      for (int j = 0; j < 4; ++j) acc[s][i][j] = fz;

  const int srow = lane >> 2;
  const int sk   = lane & 3;

  auto stage = [&](int buf, int k0) {
#pragma unroll
    for (int r = 0; r < 2; ++r) {
      const int c      = wave * 2 + r;
      const int row    = c * 16 + srow;
      const int gchunk = sk ^ (row & 3);
      const bf16* ga = A + (size_t)(m0 + row) * K + k0 + gchunk * 8;
      __builtin_amdgcn_global_load_lds((const AS1 void*)ga,
          (AS3 void*)(Asl + buf * 4096 + c * 512), 16, 0, 0);
#pragma unroll
      for (int s = 0; s < 3; ++s) {
        const bf16* gb = Bp[s] + (size_t)(n0 + row) * K + k0 + gchunk * 8;
        __builtin_amdgcn_global_load_lds((const AS1 void*)gb,
            (AS3 void*)(&Bsl[s][buf * 4096 + c * 512]), 16, 0, 0);
      }
    }
  };

  const int nk = K >> 5;   // 32
  stage(0, 0);
  for (int it = 0; it < nk; ++it) {
    __syncthreads();
    if (it + 1 < nk) stage((it + 1) & 1, (it + 1) << 5);
    const bf16* As = Asl + (it & 1) * 4096;

    bf16x8 af[4];
#pragma unroll
    for (int i = 0; i < 4; ++i) {
      const int r = wr * 64 + i * 16 + col;
      af[i] = *(const bf16x8*)&As[r * 32 + ((quad ^ (col & 3)) * 8)];
    }
#pragma unroll
    for (int s = 0; s < 3; ++s) {
      const bf16* Bs = &Bsl[s][(it & 1) * 4096];
      bf16x8 bfr[4];
#pragma unroll
      for (int j = 0; j < 4; ++j) {
        const int r = wc * 64 + j * 16 + col;
        bfr[j] = *(const bf16x8*)&Bs[r * 32 + ((quad ^ (col & 3)) * 8)];
      }
#pragma unroll
      for (int i = 0; i < 4; ++i)
#pragma unroll
        for (int j = 0; j < 4; ++j)
          acc[s][i][j] = __builtin_amdgcn_mfma_f32_16x16x32_bf16(af[i], bfr[j], acc[s][i][j], 0, 0, 0);
    }
  }

  // ---- epilogue: Q (scaled), K plain, V transposed ----
#pragma unroll
  for (int s = 0; s < 3; ++s) {
    const float sc = (s == 0) ? qscale : 1.0f;
#pragma unroll
    for (int i = 0; i < 4; ++i) {
#pragma unroll
      for (int j = 0; j < 4; ++j) {
        const int gm0 = m0 + wr * 64 + i * 16 + quad * 4;
        const int gn  = n0 + wc * 64 + j * 16 + col;
        if (s == 2) {
          bf16x4 ob;
#pragma unroll
          for (int r = 0; r < 4; ++r) ob[r] = (bf16)(acc[s][i][j][r]);
          const int bb = gm0 >> 11;        // m = bb*2048 + t
          const int t_ = gm0 & 2047;
          *(bf16x4*)&Vto[((size_t)(bb * 1024 + gn)) * 2048 + t_] = ob;
        } else {
          bf16* C = (s == 0) ? Qo : Ko;
#pragma unroll
          for (int r = 0; r < 4; ++r)
            C[(size_t)(gm0 + r) * N + gn] = (bf16)(acc[s][i][j][r] * sc);
        }
      }
    }
  }
}

__global__ __launch_bounds__(256, 2)
void gemm_o(const bf16* __restrict__ A, const bf16* __restrict__ W, float* __restrict__ C) {
  __shared__ bf16 Asl[2 * 4096];
  __shared__ bf16 Bsl[2 * 4096];
  gemm_body_f32(A, W, C, 8192, 1024, 1024, Asl, Bsl);
}

// ---------------- flash causal attention, S^T, 8 waves x 1 q-strip ----------------
// (unchanged from R12 — verified: attn dropped out of the top-5 dispatches)
// Q pre-scaled by 0.125*log2(e). Vt: [(b*1024+n), t].
// KVBLK=128 (17 paired iters), l via ones-MFMA, XCD-grouped block decode,
// T13 defer-rescale, T5 setprio, direct-to-global epilogue, R7 pairing.
__global__ __launch_bounds__(512, 4)
void attn_flash(const bf16* __restrict__ Q, const bf16* __restrict__ K,
                const bf16* __restrict__ Vt, bf16* __restrict__ Y) {
  __shared__ bf16 Ksb0[2 * 8192];   // [buf][128 keys][64 d]   32KB
  __shared__ bf16 Vsb0[2 * 8192];   // [buf][64 d][128 t]      32KB

  const int tid  = threadIdx.x;
  const int lane = tid & 63, wave = tid >> 6;   // wave 0..7
  const int quad = lane >> 4, col = lane & 15;

  // XCD-grouped decode: XCD g = bid&7 handles bh in [g*8, g*8+8)
  const int B_ = blockIdx.x;            // 0..511
  const int bh = (B_ & 7) * 8 + (B_ >> 6);
  const int p  = (B_ >> 3) & 7;         // pair index 0..7
  const int h  = bh & 15;
  const int b  = bh >> 4;
  const int hc = h * 64;
  const size_t rowBase = (size_t)b * SQLEN;

  const int srow8 = lane >> 3;
  const int sch   = lane & 7;
  const int a7    = col & 7;

  auto stageKV = [&](int buf, int t0) {
#pragma unroll
    for (int i = 0; i < 2; ++i) {
      const int krow = wave * 16 + i * 8 + srow8;          // krow&7 == srow8
      const int kch  = sch ^ srow8;
      const bf16* gk = K + (rowBase + t0 + krow) * EMB + hc + kch * 8;
      __builtin_amdgcn_global_load_lds((const AS1 void*)gk,
          (AS3 void*)(Ksb0 + buf * 8192 + wave * 1024 + i * 512), 16, 0, 0);
      const int vrow = wave * 8 + i * 4 + (lane >> 4);
      const int vch  = (lane & 15) ^ (vrow & 7);
      const bf16* gv = Vt + ((size_t)(b * EMB + hc + vrow)) * SQLEN + t0 + vch * 8;
      __builtin_amdgcn_global_load_lds((const AS1 void*)gv,
          (AS3 void*)(Vsb0 + buf * 8192 + wave * 1024 + i * 512), 16, 0, 0);
    }
  };

  const s16x4 ones = {(short)0x3F80, (short)0x3F80, (short)0x3F80, (short)0x3F80};

  for (int halfIdx = 0; halfIdx < 2; ++halfIdx) {
    const int qt = halfIdx == 0 ? (15 - p) : p;  // paired: ntt sums to 17
    const int q0 = qt * 128;
    const int ntt = qt + 1;                      // 128-key tiles

    stageKV(0, 0);

    bf16x8 qf0, qf1;
    {
      const int row = wave * 16 + col;
      const bf16* gq = Q + (rowBase + q0 + row) * EMB + hc + quad * 8;
      qf0 = *(const bf16x8*)gq;
      qf1 = *(const bf16x8*)(gq + 32);
    }
    __syncthreads();   // K/V tile 0 staged

    float m_i = -INFINITY;
    f32x4 o[4], ol;
    const f32x4 fz = {0.f, 0.f, 0.f, 0.f};
#pragma unroll
    for (int dd = 0; dd < 4; ++dd) o[dd] = fz;
    ol = fz;

    for (int tt = 0; tt < ntt; ++tt) {
      const int t0 = tt * 128;
      const int cur = tt & 1;
      if (tt + 1 < ntt) stageKV(cur ^ 1, t0 + 128);  // prefetch in flight
      const bf16* Ks = Ksb0 + cur * 8192;
      const bf16* Vs = Vsb0 + cur * 8192;

      // ---- S^T: 8 slabs of 16 keys ----
      f32x4 s[8];
      __builtin_amdgcn_s_setprio(1);
#pragma unroll
      for (int sl = 0; sl < 8; ++sl) {
        const bf16x8 kf0 = *(const bf16x8*)&Ks[(sl * 16 + col) * 64 + ((quad ^ a7) * 8)];
        const bf16x8 kf1 = *(const bf16x8*)&Ks[(sl * 16 + col) * 64 + (((quad ^ 4) ^ a7) * 8)];
        f32x4 z = fz;
        z = __builtin_amdgcn_mfma_f32_16x16x32_bf16(kf0, qf0, z, 0, 0, 0);
        s[sl] = __builtin_amdgcn_mfma_f32_16x16x32_bf16(kf1, qf1, z, 0, 0, 0);
      }
      __builtin_amdgcn_s_setprio(0);

      if (tt == qt) {  // single diagonal tile: global-index causal mask
        const int qg = q0 + wave * 16 + col;
#pragma unroll
        for (int sl = 0; sl < 8; ++sl)
#pragma unroll
          for (int r = 0; r < 4; ++r)
            if (t0 + sl * 16 + quad * 4 + r > qg) s[sl][r] = -INFINITY;
      }

      // ---- online softmax (T13 defer-rescale); l via ones-MFMA below ----
      bf16x4 pb[8];
      {
        float mx = s[0][0];
#pragma unroll
        for (int sl = 0; sl < 8; ++sl)
#pragma unroll
          for (int r = 0; r < 4; ++r) mx = fmaxf(mx, s[sl][r]);
        mx = fmaxf(mx, __shfl_xor(mx, 16));
        mx = fmaxf(mx, __shfl_xor(mx, 32));
        if (!__all(mx <= m_i + 8.f)) {   // rescale only on real max growth
          const float mnew = fmaxf(m_i, mx);
          const float a = __builtin_amdgcn_exp2f(m_i - mnew);
#pragma unroll
          for (int dd = 0; dd < 4; ++dd) o[dd] *= a;
          ol *= a;
          m_i = mnew;
        }
#pragma unroll
        for (int sl = 0; sl < 8; ++sl)
#pragma unroll
          for (int r = 0; r < 4; ++r)
            pb[sl][r] = (bf16)__builtin_amdgcn_exp2f(s[sl][r] - m_i);  // <= 2^8
      }

      // ---- O^T += V^T P^T; l += 1^T P^T (ones-MFMA) ----
      __builtin_amdgcn_s_setprio(1);
#pragma unroll
      for (int sl = 0; sl < 8; ++sl) {
        const s16x4 pf = __builtin_bit_cast(s16x4, pb[sl]);
        ol = __builtin_amdgcn_mfma_f32_16x16x16bf16_1k(ones, pf, ol, 0, 0, 0);
        const int cch  = 2 * sl + (quad >> 1);   // 0..15
        const int half = quad & 1;
#pragma unroll
        for (int dd = 0; dd < 4; ++dd) {
          const int row = dd * 16 + col;
          const bf16x4 vb = *(const bf16x4*)&Vs[row * 128 + ((cch ^ a7) * 8) + half * 4];
          const s16x4 vf = __builtin_bit_cast(s16x4, vb);
          o[dd] = __builtin_amdgcn_mfma_f32_16x16x16bf16_1k(vf, pf, o[dd], 0, 0, 0);
        }
      }
      __builtin_amdgcn_s_setprio(0);
      __syncthreads();  // drains prefetch; guards dbuf reuse
    }

    // ---- epilogue: O^T/l straight to global (l replicated in every ol lane) ----
    {
      const float rl = __builtin_amdgcn_rcpf(ol[0]);
      const size_t yrow = (rowBase + q0 + wave * 16 + col) * EMB + hc;
#pragma unroll
      for (int dd = 0; dd < 4; ++dd) {
        bf16x4 ob;
#pragma unroll
        for (int r = 0; r < 4; ++r) ob[r] = (bf16)(o[dd][r] * rl);
        *(bf16x4*)&Y[yrow + dd * 16 + quad * 4] = ob;
      }
    }
  }
}

// ---------------- launcher ----------------
extern "C" void kernel_launch(void* const* d_in, const int* in_sizes, int n_in,
                              void* d_out, int out_size, void* d_ws, size_t ws_size,
                              hipStream_t stream) {
  const float* x  = (const float*)d_in[0];
  const float* Wq = (const float*)d_in[1];
  const float* Wk = (const float*)d_in[2];
  const float* Wv = (const float*)d_in[3];
  const float* Wo = (const float*)d_in[4];
  float* out = (float*)d_out;

  const size_t ME = 8192ull * 1024ull;
  const size_t WE = 1024ull * 1024ull;
  bf16* ws  = (bf16*)d_ws;
  bf16* xb  = ws;
  bf16* wqb = xb + ME;
  bf16* wkb = wqb + WE;
  bf16* wvb = wkb + WE;
  bf16* wob = wvb + WE;
  bf16* Qb  = wob + WE;
  bf16* Kb  = Qb + ME;
  bf16* Vtb = Kb + ME;   // V written directly transposed by gemm_qkv
  bf16* Yb  = Vtb + ME;

  cvt_f32_bf16<<<(int)(ME / 8 / 256), 256, 0, stream>>>(x, xb, (int)(ME / 8));
  cvt_w4<<<dim3((int)(WE / 8 / 256), 4), 256, 0, stream>>>(Wq, Wk, Wv, Wo, wqb, wkb, wvb, wob, (int)(WE / 8));

  const float qscale = 0.125f * 1.4426950408889634f;
  gemm_qkv<<<dim3(64, 8), 256, 0, stream>>>(xb, wqb, wkb, wvb, Qb, Kb, Vtb, qscale);

  attn_flash<<<512, 512, 0, stream>>>(Qb, Kb, Vtb, Yb);

  gemm_o<<<dim3(64, 8), 256, 0, stream>>>(Yb, wob, out);
}